// Round 1
// baseline (6770.878 us; speedup 1.0000x reference)
//
#include <hip/hip_runtime.h>
#include <hip/hip_bf16.h>
#include <stdint.h>

#define GM 4096
#define GK 2048
#define GN 5632
#define GE 8
#define GTOPK 2

typedef __attribute__((ext_vector_type(4))) float f32x4;
typedef __attribute__((ext_vector_type(8))) short short8;
typedef __attribute__((ext_vector_type(4))) uint32_t u32x4;

__device__ __forceinline__ void gld16(const void* g, void* l) {
  __builtin_amdgcn_global_load_lds((const __attribute__((address_space(1))) void*)g,
                                   (__attribute__((address_space(3))) void*)l, 16, 0, 0);
}

// pack hi16(hi),hi16(lo) -> one u32 holding two bf16 (truncation, 1 v_perm_b32)
__device__ __forceinline__ uint32_t pack2(float hi, float lo) {
  return __builtin_amdgcn_perm(__float_as_uint(hi), __float_as_uint(lo), 0x07060302u);
}

__device__ __forceinline__ unsigned short bf16rne(float f) {
  uint32_t u = __float_as_uint(f);
  u += 0x7FFFu + ((u >> 16) & 1u);
  return (unsigned short)(u >> 16);
}

// ---------------- routing ----------------
__global__ void route_count(const int* __restrict__ ids, int* __restrict__ counts) {
  int i = blockIdx.x * blockDim.x + threadIdx.x;
  if (i < GM * GTOPK) atomicAdd(&counts[ids[i]], 1);
}

__global__ void route_scan(const int* __restrict__ counts, int* __restrict__ offs) {
  if (threadIdx.x == 0) {
    int s = 0;
    for (int e = 0; e < GE; ++e) { offs[e] = s; s += counts[e]; }
    offs[GE] = s;
  }
}

__global__ void route_scatter(const int* __restrict__ ids, const float* __restrict__ wts,
                              const int* __restrict__ offs, int* __restrict__ fill,
                              int* __restrict__ slot_token, float* __restrict__ slot_gate) {
  int i = blockIdx.x * blockDim.x + threadIdx.x;
  if (i < GM * GTOPK) {
    int e = ids[i];
    int pos = offs[e] + atomicAdd(&fill[e], 1);
    slot_token[pos] = i / GTOPK;
    slot_gate[pos] = wts[i];
  }
}

// ---------------- hs fp32 -> bf16 ----------------
__global__ void cvt_bf16(const float* __restrict__ x, unsigned short* __restrict__ y, int n8) {
  int i = blockIdx.x * blockDim.x + threadIdx.x;
  if (i >= n8) return;
  const f32x4* xp = (const f32x4*)x;
  f32x4 a = xp[2 * i], b = xp[2 * i + 1];
  u32x4 o;
  o.x = ((uint32_t)bf16rne(a.y) << 16) | bf16rne(a.x);
  o.y = ((uint32_t)bf16rne(a.w) << 16) | bf16rne(a.z);
  o.z = ((uint32_t)bf16rne(b.y) << 16) | bf16rne(b.x);
  o.w = ((uint32_t)bf16rne(b.w) << 16) | bf16rne(b.z);
  ((u32x4*)y)[i] = o;
}

// ---------------- fused grouped GEMM ----------------
// MODE 1: act[slot, 0:N] = silu(h@w1g^T) * (h@w1u^T)   (A = hs_bf16 gathered by slot_token)
// MODE 2: out[token, :]  += gate * (act @ w2^T)          (A = act, rows = slots directly)
// Tile: BM=128 x BN=128 x BK=32, 4 waves (2x2), each wave 64x64 via 4x4 mfma_16x16x32_bf16.
// LDS layout is fragment-permuted: every ds_read_b128 address == subtile_base + lane*16
// (conflict-free) and matches global_load_lds's base+lane*16 destination rule.
template <int MODE>
__global__ __launch_bounds__(256, 2)
void moe_gemm(const unsigned short* __restrict__ A,
              const float* __restrict__ B,
              const int* __restrict__ offs,
              const int* __restrict__ slot_token,
              const float* __restrict__ slot_gate,
              unsigned short* __restrict__ act,
              float* __restrict__ out)
{
  constexpr int KR = (MODE == 1) ? GK : GN;  // reduction length == row length of A and B
  const int e = blockIdx.z;
  const int segs = offs[e];
  const int segc = offs[e + 1] - segs;
  const int mtile = blockIdx.x;
  if (mtile * 128 >= segc) return;           // dynamic segment: most x-blocks early-exit
  const int ntile = blockIdx.y;
  const int tid = threadIdx.x;
  const int w = tid >> 6, lane = tid & 63;
  const int wm = w >> 1, wn = w & 1;

  __shared__ __align__(16) char lds[24 * 1024];  // A: 8KB bf16, B: 16KB fp32

  const float* Be = B + (size_t)e * (size_t)((MODE == 1) ? (2 * GN * GK) : (GK * GN));

  // ---- A staging source pointers (2 calls/thread, 16B bf16x8 each) ----
  const char* aptr[2];
  {
    int m16 = lane & 15, h = lane >> 4;
    #pragma unroll
    for (int c = 0; c < 2; ++c) {
      int s = c * 4 + w;                       // subtile 0..7 (16 rows each)
      int slot = segs + mtile * 128 + s * 16 + m16;
      if (slot >= segs + segc) slot = segs;    // clamp: safe row, masked in epilogue
      size_t arow = (MODE == 1) ? (size_t)slot_token[slot] : (size_t)slot;
      aptr[c] = (const char*)(A + arow * KR + h * 8);
    }
  }
  // ---- B staging source pointers (4 calls/thread, 16B fp32x4 each) ----
  const char* bptr[4];
  {
    int n16 = lane & 15, k4hi = lane >> 4;
    #pragma unroll
    for (int c = 0; c < 4; ++c) {
      int q = c * 4 + w;                       // 16 wave-units: subtile s, half hh
      int s = q >> 1, hh = q & 1;
      int k4 = hh * 4 + k4hi;
      int brow;
      if (MODE == 1)  // subtiles 0-3: gate rows, 4-7: up rows (same output cols -> in-reg silu)
        brow = (s < 4) ? (ntile * 64 + s * 16 + n16) : (GN + ntile * 64 + (s - 4) * 16 + n16);
      else
        brow = ntile * 128 + s * 16 + n16;
      bptr[c] = (const char*)(Be + (size_t)brow * KR + k4 * 4);
    }
  }
  char* ldsAdst0 = lds + w * 1024;
  char* ldsAdst1 = lds + (4 + w) * 1024;
  char* ldsBdst[4];
  #pragma unroll
  for (int c = 0; c < 4; ++c) ldsBdst[c] = lds + 8192 + (c * 4 + w) * 1024;

  const f32x4 zero4 = {0.f, 0.f, 0.f, 0.f};
  f32x4 acc[4][4];
  #pragma unroll
  for (int a_ = 0; a_ < 4; ++a_)
    #pragma unroll
    for (int b_ = 0; b_ < 4; ++b_) acc[a_][b_] = zero4;

  const char* ldsAfr = lds + (wm * 4) * 1024 + lane * 16;

  for (int k0 = 0; k0 < KR; k0 += 32) {
    gld16(aptr[0] + (size_t)k0 * 2, ldsAdst0);
    gld16(aptr[1] + (size_t)k0 * 2, ldsAdst1);
    #pragma unroll
    for (int c = 0; c < 4; ++c) gld16(bptr[c] + (size_t)k0 * 4, ldsBdst[c]);
    __syncthreads();  // compiler emits vmcnt(0) drain before s_barrier

    short8 afr[4];
    #pragma unroll
    for (int mt = 0; mt < 4; ++mt) afr[mt] = *(const short8*)(ldsAfr + mt * 1024);
    #pragma unroll
    for (int j = 0; j < 4; ++j) {
      int sB = (MODE == 1) ? ((j < 2) ? (wn * 2 + j) : (4 + wn * 2 + j - 2)) : (wn * 4 + j);
      const char* lb = lds + 8192 + sB * 2048 + ((lane >> 4) * 32 + (lane & 15)) * 16;
      f32x4 b0 = *(const f32x4*)lb;
      f32x4 b1 = *(const f32x4*)(lb + 256);
      union { uint32_t u[4]; short8 s8; } bu;
      bu.u[0] = pack2(b0.y, b0.x);
      bu.u[1] = pack2(b0.w, b0.z);
      bu.u[2] = pack2(b1.y, b1.x);
      bu.u[3] = pack2(b1.w, b1.z);
      #pragma unroll
      for (int mt = 0; mt < 4; ++mt)
        acc[mt][j] = __builtin_amdgcn_mfma_f32_16x16x32_bf16(afr[mt], bu.s8, acc[mt][j], 0, 0, 0);
    }
    __syncthreads();
  }

  // ---- epilogue: C/D mapping col=lane&15, row=(lane>>4)*4+r ----
  int lcol = lane & 15;
  int rbase = (lane >> 4) * 4;
  if (MODE == 1) {
    #pragma unroll
    for (int mt = 0; mt < 4; ++mt) {
      int mloc = mtile * 128 + wm * 64 + mt * 16 + rbase;
      #pragma unroll
      for (int j = 0; j < 2; ++j) {
        int col = ntile * 64 + wn * 32 + j * 16 + lcol;
        f32x4 g = acc[mt][j], u = acc[mt][2 + j];  // identical lane mapping -> in-reg silu
        #pragma unroll
        for (int r = 0; r < 4; ++r) {
          int ml = mloc + r;
          if (ml < segc) {
            float gv = g[r];
            float s = gv / (1.f + __expf(-gv));
            act[(size_t)(segs + ml) * GN + col] = bf16rne(s * u[r]);
          }
        }
      }
    }
  } else {
    #pragma unroll
    for (int mt = 0; mt < 4; ++mt) {
      int mloc = mtile * 128 + wm * 64 + mt * 16 + rbase;
      #pragma unroll
      for (int r = 0; r < 4; ++r) {
        int ml = mloc + r;
        if (ml < segc) {
          int slot = segs + ml;
          int token = slot_token[slot];
          float gate = slot_gate[slot];
          float* orow = out + (size_t)token * GK;
          #pragma unroll
          for (int j = 0; j < 4; ++j) {
            int col = ntile * 128 + wn * 64 + j * 16 + lcol;
            atomicAdd(&orow[col], gate * acc[mt][j][r]);
          }
        }
      }
    }
  }
}

extern "C" void kernel_launch(void* const* d_in, const int* in_sizes, int n_in,
                              void* d_out, int out_size, void* d_ws, size_t ws_size,
                              hipStream_t stream) {
  const float* hs  = (const float*)d_in[0];
  const float* w1  = (const float*)d_in[1];
  const float* w2  = (const float*)d_in[2];
  const float* tkw = (const float*)d_in[3];
  const int*   tki = (const int*)d_in[4];
  float* out = (float*)d_out;

  char* ws = (char*)d_ws;
  int*   counts     = (int*)(ws + 0);
  int*   fill       = (int*)(ws + 64);
  int*   offs       = (int*)(ws + 128);
  int*   slot_token = (int*)(ws + 1024);
  float* slot_gate  = (float*)(ws + 1024 + 32768);
  unsigned short* hsb = (unsigned short*)(ws + 131072);
  unsigned short* act = (unsigned short*)(ws + 131072 + (size_t)GM * GK * 2);
  // ws need: 131072 + 16.8MB (hs bf16) + 92.3MB (act bf16) ~= 109 MB

  hipMemsetAsync(ws, 0, 1024, stream);
  hipMemsetAsync(d_out, 0, (size_t)out_size * sizeof(float), stream);

  route_count<<<(GM * GTOPK + 255) / 256, 256, 0, stream>>>(tki, counts);
  route_scan<<<1, 64, 0, stream>>>(counts, offs);
  route_scatter<<<(GM * GTOPK + 255) / 256, 256, 0, stream>>>(tki, tkw, offs, fill,
                                                              slot_token, slot_gate);
  cvt_bf16<<<(GM * GK / 8 + 255) / 256, 256, 0, stream>>>(hs, hsb, GM * GK / 8);

  // x = m-tiles (fastest) so co-resident blocks share the same B slab -> L2/L3 reuse
  moe_gemm<1><<<dim3(64, GN / 64, GE), 256, 0, stream>>>(hsb, w1, offs, slot_token,
                                                         slot_gate, act, nullptr);
  moe_gemm<2><<<dim3(64, GK / 128, GE), 256, 0, stream>>>(act, w2, offs, slot_token,
                                                          slot_gate, nullptr, out);
}